// Round 1
// baseline (254.280 us; speedup 1.0000x reference)
//
#include <hip/hip_runtime.h>
#include <hip/hip_bf16.h>

// BehaviorSpecificPFF: grouped-GEMM implementation.
// Pipeline: scan/compact tokens by behavior -> convert weights to bf16 ->
// zero padding rows of out -> gather x rows (bf16) -> GEMM1(+bias+relu) ->
// GEMM2 -> residual+LayerNorm+scatter.

#define NTOK 16384   // B*T = 8*2048
#define DM   512     // d_model
#define DF   2048    // d_ff
#define NB   4       // behaviors (excluding padding class 0)

typedef __attribute__((ext_vector_type(8))) short bf16x8;
typedef __attribute__((ext_vector_type(4))) float f32x4;
typedef __attribute__((ext_vector_type(4))) unsigned short u16x4;
typedef __attribute__((ext_vector_type(8))) unsigned short u16x8;

__device__ inline unsigned short f2bf(float f) {
  union { float f; unsigned u; } x; x.f = f;
  unsigned r = x.u + 0x7fffu + ((x.u >> 16) & 1u);   // RNE
  return (unsigned short)(r >> 16);
}
__device__ inline float bf2f(unsigned short h) {
  union { unsigned u; float f; } x; x.u = ((unsigned)h) << 16; return x.f;
}
__device__ inline void gload16(const void* g, void* l) {
  __builtin_amdgcn_global_load_lds(
      (const __attribute__((address_space(1))) unsigned int*)g,
      (__attribute__((address_space(3))) unsigned int*)l, 16, 0, 0);
}

// ---------------------------------------------------------------------------
// Header layout in ws (uint32): [0..3]=cnt[4], [4..7]=segoff[4] (row offsets,
// 128-aligned segments), [8..11]=segpad[4] (=align128(cnt)), [12]=total_padded
// ---------------------------------------------------------------------------

// Deterministic per-behavior compaction. One block per behavior; each block
// counts all behaviors itself (no global atomics), then does an ordered
// ballot-based compaction of its own token list.
__global__ void k_scan(const int* __restrict__ bseq, unsigned* __restrict__ hdr,
                       int* __restrict__ tok) {
  const int beh = blockIdx.x;
  const int tid = threadIdx.x;
  const int lane = tid & 63, wid = tid >> 6;
  __shared__ unsigned scnt[NB];
  __shared__ unsigned wtot[4];
  if (tid < NB) scnt[tid] = 0;
  __syncthreads();
  unsigned lc[NB] = {0, 0, 0, 0};
  for (int t = tid; t < NTOK; t += 256) {
    int v = bseq[t];
    if (v > 0) lc[v - 1]++;
  }
  for (int c = 0; c < NB; c++)
    if (lc[c]) atomicAdd(&scnt[c], lc[c]);
  __syncthreads();
  unsigned cnt[NB];
  for (int c = 0; c < NB; c++) cnt[c] = scnt[c];
  unsigned segoff = 0;
  for (int m = 0; m < beh; m++) segoff += (cnt[m] + 127u) & ~127u;
  if (beh == 0) {
    if (tid < NB) {
      hdr[tid] = cnt[tid];
      hdr[8 + tid] = (cnt[tid] + 127u) & ~127u;
    }
    if (tid == 0) {
      unsigned o = 0;
      for (int n = 0; n < NB; n++) { hdr[4 + n] = o; o += (cnt[n] + 127u) & ~127u; }
      hdr[12] = o;
    }
  }
  unsigned base = segoff;
  for (int c0 = 0; c0 < NTOK; c0 += 256) {
    int t = c0 + tid;
    bool f = (bseq[t] == beh + 1);
    unsigned long long mask = __ballot(f);
    unsigned rank = __popcll(mask & ((1ull << lane) - 1ull));
    if (lane == 0) wtot[wid] = (unsigned)__popcll(mask);
    __syncthreads();
    unsigned pre = 0, tot = 0;
    for (int w = 0; w < 4; w++) { if (w < wid) pre += wtot[w]; tot += wtot[w]; }
    if (f) tok[base + pre + rank] = t;
    base += tot;
    __syncthreads();
  }
}

// fp32 -> bf16 bulk convert (weights)
__global__ void k_cvt(const float* __restrict__ s, unsigned short* __restrict__ d, int n) {
  int i = (blockIdx.x * blockDim.x + threadIdx.x) * 4;
  int st = gridDim.x * blockDim.x * 4;
  for (; i < n; i += st) {
    float4 v = *(const float4*)(s + i);
    u16x4 o = {f2bf(v.x), f2bf(v.y), f2bf(v.z), f2bf(v.w)};
    *(u16x4*)(d + i) = o;
  }
}

// Zero the output rows of padding tokens (b_seq == 0).
__global__ void k_zeropad(const int* __restrict__ b, float4* __restrict__ o, int n4) {
  int i = blockIdx.x * blockDim.x + threadIdx.x;
  int st = gridDim.x * blockDim.x;
  for (; i < n4; i += st) {
    if (b[i >> 7] == 0) o[i] = make_float4(0.f, 0.f, 0.f, 0.f);
  }
}

// Gather x rows into compacted bf16 matrix xg[row][512]; zero tail pad rows.
__global__ void k_gather(const float* __restrict__ x, const int* __restrict__ tok,
                         const unsigned* __restrict__ hdr, unsigned short* __restrict__ xg) {
  const int wid = threadIdx.x >> 6, lane = threadIdx.x & 63;
  const int s = blockIdx.x * 4 + wid;
  if (s >= (int)hdr[12]) return;
  int beh = 0;
  while (beh < 3 && (unsigned)s >= hdr[4 + beh] + hdr[8 + beh]) beh++;
  unsigned local = (unsigned)s - hdr[4 + beh];
  u16x8 v;
  if (local < hdr[beh]) {
    int t = tok[s];
    const float4* xp = (const float4*)(x + (size_t)t * DM + lane * 8);
    float4 a = xp[0], b2 = xp[1];
    v[0] = f2bf(a.x); v[1] = f2bf(a.y); v[2] = f2bf(a.z); v[3] = f2bf(a.w);
    v[4] = f2bf(b2.x); v[5] = f2bf(b2.y); v[6] = f2bf(b2.z); v[7] = f2bf(b2.w);
  } else {
    for (int i = 0; i < 8; i++) v[i] = 0;
  }
  *(u16x8*)(xg + (size_t)s * DM + lane * 8) = v;
}

// ---------------------------------------------------------------------------
// Grouped GEMM: C[M, Ntot] = A[M, K] * W[beh][Ntot, K]^T  (K contiguous both)
// 128x128 tile, BK=32, 256 threads (4 waves, each a 64x64 quadrant of 4x4
// 16x16x32 bf16 MFMA fragments). LDS layout: chunk-of-8 [kb][row][8] so
// global_load_lds (linear lane*16B dest) and ds_read_b128 both line up.
// RB: apply bias + relu (GEMM1). Output bf16, ld = Ntot = gridDim.y*128.
// ---------------------------------------------------------------------------
template <bool RB>
__global__ __launch_bounds__(256) void k_gemm(
    const unsigned short* __restrict__ A, const unsigned short* __restrict__ W,
    const float* __restrict__ bias, unsigned short* __restrict__ Out,
    const unsigned* __restrict__ hdr, int K) {
  const int Ntot = gridDim.y * 128;
  const int rt = blockIdx.x, nt = blockIdx.y, beh = blockIdx.z;
  const unsigned rows_padded = hdr[8 + beh];
  if ((unsigned)(rt * 128) >= rows_padded) return;
  const int rowbase = (int)hdr[4 + beh] + rt * 128;
  const unsigned short* Ab = A + (size_t)rowbase * K;
  const unsigned short* Wb = W + (size_t)beh * K * Ntot + (size_t)(nt * 128) * K;

  __shared__ unsigned short lsA[128 * 32];
  __shared__ unsigned short lsB[128 * 32];

  const int tid = threadIdx.x, lane = tid & 63, wid = tid >> 6;
  const int wr = wid >> 1, wc = wid & 1;

  f32x4 acc[4][4];
#pragma unroll
  for (int m = 0; m < 4; m++)
#pragma unroll
    for (int n = 0; n < 4; n++) acc[m][n] = (f32x4){0.f, 0.f, 0.f, 0.f};

  const int kb = lane >> 4, rl = lane & 15;
  const bf16x8* As = (const bf16x8*)lsA;
  const bf16x8* Bs = (const bf16x8*)lsB;

  for (int k0 = 0; k0 < K; k0 += 32) {
#pragma unroll
    for (int j = 0; j < 2; j++) {
      int cb = (wid * 2 + j) * 64;          // wave-uniform chunk base (of 512)
      int chunk = cb + lane;
      int r = chunk & 127, kk = chunk >> 7; // row in tile, k-block 0..3
      gload16(Ab + (size_t)r * K + k0 + kk * 8, (void*)&lsA[cb * 8]);
      gload16(Wb + (size_t)r * K + k0 + kk * 8, (void*)&lsB[cb * 8]);
    }
    __syncthreads();
    bf16x8 af[4], bfv[4];
#pragma unroll
    for (int m = 0; m < 4; m++) af[m] = As[kb * 128 + wr * 64 + m * 16 + rl];
#pragma unroll
    for (int n = 0; n < 4; n++) bfv[n] = Bs[kb * 128 + wc * 64 + n * 16 + rl];
#pragma unroll
    for (int m = 0; m < 4; m++)
#pragma unroll
      for (int n = 0; n < 4; n++)
        acc[m][n] = __builtin_amdgcn_mfma_f32_16x16x32_bf16(af[m], bfv[n], acc[m][n], 0, 0, 0);
    __syncthreads();
  }

  const int rj = (lane >> 4) * 4, cl = lane & 15;
#pragma unroll
  for (int n = 0; n < 4; n++) {
    const int col = nt * 128 + wc * 64 + n * 16 + cl;
    float bv = 0.f;
    if (RB) bv = bias[beh * Ntot + col];
#pragma unroll
    for (int m = 0; m < 4; m++) {
      const int row0 = rowbase + wr * 64 + m * 16 + rj;
#pragma unroll
      for (int j = 0; j < 4; j++) {
        float v = acc[m][n][j] + bv;
        if (RB) v = fmaxf(v, 0.f);
        Out[(size_t)(row0 + j) * Ntot + col] = f2bf(v);
      }
    }
  }
}

// Residual + LayerNorm + gamma/beta + scatter. One wave per compacted row.
__global__ void k_ln(const unsigned short* __restrict__ yb, const float* __restrict__ x,
                     const float* __restrict__ b2, const float* __restrict__ gamma,
                     const float* __restrict__ beta, const int* __restrict__ tok,
                     const unsigned* __restrict__ hdr, float* __restrict__ out) {
  const int wid = threadIdx.x >> 6, lane = threadIdx.x & 63;
  const int s = blockIdx.x * 4 + wid;
  if (s >= (int)hdr[12]) return;
  int beh = 0;
  while (beh < 3 && (unsigned)s >= hdr[4 + beh] + hdr[8 + beh]) beh++;
  unsigned local = (unsigned)s - hdr[4 + beh];
  if (local >= hdr[beh]) return;  // tail pad row
  const int t = tok[s];
  const int d0 = lane * 8;
  const float4* xp = (const float4*)(x + (size_t)t * DM + d0);
  float4 xa = xp[0], xb = xp[1];
  u16x8 y = *(const u16x8*)(yb + (size_t)s * DM + d0);
  const float* b2p = b2 + beh * DM + d0;
  float r[8];
  r[0] = xa.x + bf2f(y[0]) + b2p[0];
  r[1] = xa.y + bf2f(y[1]) + b2p[1];
  r[2] = xa.z + bf2f(y[2]) + b2p[2];
  r[3] = xa.w + bf2f(y[3]) + b2p[3];
  r[4] = xb.x + bf2f(y[4]) + b2p[4];
  r[5] = xb.y + bf2f(y[5]) + b2p[5];
  r[6] = xb.z + bf2f(y[6]) + b2p[6];
  r[7] = xb.w + bf2f(y[7]) + b2p[7];
  float sum = 0.f, sq = 0.f;
#pragma unroll
  for (int i = 0; i < 8; i++) { sum += r[i]; sq += r[i] * r[i]; }
  for (int off = 32; off; off >>= 1) {
    sum += __shfl_xor(sum, off, 64);
    sq += __shfl_xor(sq, off, 64);
  }
  const float mu = sum * (1.f / 512.f);
  const float var = sq * (1.f / 512.f) - mu * mu;
  const float rs = rsqrtf(var + 1e-5f);
  const float* gp = gamma + beh * DM + d0;
  const float* bp = beta + beh * DM + d0;
  float o[8];
#pragma unroll
  for (int i = 0; i < 8; i++) o[i] = (r[i] - mu) * rs * gp[i] + bp[i];
  float4* op = (float4*)(out + (size_t)t * DM + d0);
  op[0] = make_float4(o[0], o[1], o[2], o[3]);
  op[1] = make_float4(o[4], o[5], o[6], o[7]);
}

extern "C" void kernel_launch(void* const* d_in, const int* in_sizes, int n_in,
                              void* d_out, int out_size, void* d_ws, size_t ws_size,
                              hipStream_t stream) {
  const float* x     = (const float*)d_in[0];
  const int*   bseq  = (const int*)d_in[1];
  const float* W1    = (const float*)d_in[2];
  const float* b1    = (const float*)d_in[3];
  const float* W2    = (const float*)d_in[4];
  const float* b2    = (const float*)d_in[5];
  const float* gamma = (const float*)d_in[6];
  const float* beta  = (const float*)d_in[7];
  float* out = (float*)d_out;
  char* ws = (char*)d_ws;

  const int maxr = NTOK + 512;  // sum of 128-aligned segment sizes bound
  size_t off = 1024;
  unsigned* hdr = (unsigned*)ws;
  int* tok = (int*)(ws + off);                       off += (size_t)maxr * 4;
  off = (off + 1023) & ~(size_t)1023;
  unsigned short* w1b = (unsigned short*)(ws + off); off += (size_t)NB * DF * DM * 2;
  unsigned short* w2b = (unsigned short*)(ws + off); off += (size_t)NB * DM * DF * 2;
  unsigned short* xg  = (unsigned short*)(ws + off); off += (size_t)maxr * DM * 2;
  unsigned short* H   = (unsigned short*)(ws + off); off += (size_t)maxr * DF * 2;
  unsigned short* yb  = (unsigned short*)(ws + off); off += (size_t)maxr * DM * 2;
  // total ~115 MB of ws

  k_scan<<<NB, 256, 0, stream>>>(bseq, hdr, tok);
  k_cvt<<<1024, 256, 0, stream>>>(W1, w1b, NB * DF * DM);
  k_cvt<<<1024, 256, 0, stream>>>(W2, w2b, NB * DM * DF);
  k_zeropad<<<2048, 256, 0, stream>>>(bseq, (float4*)out, NTOK * (DM / 4));
  k_gather<<<(maxr + 3) / 4, 256, 0, stream>>>(x, tok, hdr, xg);
  k_gemm<true><<<dim3(NTOK / 128, DF / 128, NB), 256, 0, stream>>>(xg, w1b, b1, H, hdr, DM);
  k_gemm<false><<<dim3(NTOK / 128, DM / 128, NB), 256, 0, stream>>>(H, w2b, nullptr, yb, hdr, DF);
  k_ln<<<(maxr + 3) / 4, 256, 0, stream>>>(yb, x, b2, gamma, beta, tok, hdr, out);
}